// Round 1
// baseline (3235.900 us; speedup 1.0000x reference)
//
#include <hip/hip_runtime.h>
#include <math.h>

// Problem constants
#define BB 4
#define SS 2048
#define DD 1024
#define DV 64

// GEMM tiling
#define BM 64
#define BN 64
#define BK 16

// C[M,N] = A[M,K] * B[N,K]^T   (all row-major)
__global__ __launch_bounds__(256) void gemm_nt(const float* __restrict__ A,
                                               const float* __restrict__ B,
                                               float* __restrict__ C,
                                               int M, int N, int K) {
    __shared__ float As[BK][BM];
    __shared__ float Bs[BK][BN];
    const int tid = threadIdx.x;
    const int tx = tid & 15;        // 0..15 -> col group
    const int ty = tid >> 4;        // 0..15 -> row group
    const int m0 = blockIdx.y * BM;
    const int n0 = blockIdx.x * BN;
    const int lk = tid & 15;        // k within tile for loads
    const int lr = tid >> 4;        // row base for loads (0..15)

    float acc[4][4] = {};
    for (int k0 = 0; k0 < K; k0 += BK) {
#pragma unroll
        for (int i = 0; i < 4; ++i) {
            As[lk][lr + 16 * i] = A[(size_t)(m0 + lr + 16 * i) * K + k0 + lk];
            Bs[lk][lr + 16 * i] = B[(size_t)(n0 + lr + 16 * i) * K + k0 + lk];
        }
        __syncthreads();
#pragma unroll
        for (int k = 0; k < BK; ++k) {
            float a[4], b[4];
#pragma unroll
            for (int i = 0; i < 4; ++i) a[i] = As[k][ty * 4 + i];
#pragma unroll
            for (int j = 0; j < 4; ++j) b[j] = Bs[k][tx * 4 + j];
#pragma unroll
            for (int i = 0; i < 4; ++i)
#pragma unroll
                for (int j = 0; j < 4; ++j) acc[i][j] += a[i] * b[j];
        }
        __syncthreads();
    }
#pragma unroll
    for (int i = 0; i < 4; ++i)
#pragma unroll
        for (int j = 0; j < 4; ++j)
            C[(size_t)(m0 + ty * 4 + i) * N + n0 + tx * 4 + j] = acc[i][j];
}

// C[M,N] = A[M,K] * B[K,N]   (all row-major)
__global__ __launch_bounds__(256) void gemm_nn(const float* __restrict__ A,
                                               const float* __restrict__ B,
                                               float* __restrict__ C,
                                               int M, int N, int K) {
    __shared__ float As[BK][BM];
    __shared__ float Bs[BK][BN];
    const int tid = threadIdx.x;
    const int tx = tid & 15;
    const int ty = tid >> 4;
    const int m0 = blockIdx.y * BM;
    const int n0 = blockIdx.x * BN;
    const int lk = tid & 15;
    const int lr = tid >> 4;
    const int bn = tid & 63;   // B-load: col within tile
    const int bk = tid >> 6;   // B-load: k row base (0..3)

    float acc[4][4] = {};
    for (int k0 = 0; k0 < K; k0 += BK) {
#pragma unroll
        for (int i = 0; i < 4; ++i)
            As[lk][lr + 16 * i] = A[(size_t)(m0 + lr + 16 * i) * K + k0 + lk];
#pragma unroll
        for (int i = 0; i < 4; ++i)
            Bs[bk + 4 * i][bn] = B[(size_t)(k0 + bk + 4 * i) * N + n0 + bn];
        __syncthreads();
#pragma unroll
        for (int k = 0; k < BK; ++k) {
            float a[4], b[4];
#pragma unroll
            for (int i = 0; i < 4; ++i) a[i] = As[k][ty * 4 + i];
#pragma unroll
            for (int j = 0; j < 4; ++j) b[j] = Bs[k][tx * 4 + j];
#pragma unroll
            for (int i = 0; i < 4; ++i)
#pragma unroll
                for (int j = 0; j < 4; ++j) acc[i][j] += a[i] * b[j];
        }
        __syncthreads();
    }
#pragma unroll
    for (int i = 0; i < 4; ++i)
#pragma unroll
        for (int j = 0; j < 4; ++j)
            C[(size_t)(m0 + ty * 4 + i) * N + n0 + tx * 4 + j] = acc[i][j];
}

// In-place causal softmax over one row per block. sc is [S,S]; row q has
// valid entries k <= q. Mask applied before scale in ref == equivalent.
__global__ __launch_bounds__(256) void softmax_causal(float* __restrict__ sc,
                                                      int S, float scale) {
    const int q = blockIdx.x;
    float* row = sc + (size_t)q * S;
    const int n = q + 1;
    const int lane = threadIdx.x & 63;
    const int wave = threadIdx.x >> 6;
    __shared__ float red[4];

    // pass 1: max of scaled scores
    float m = -INFINITY;
    for (int k = threadIdx.x; k < n; k += 256) m = fmaxf(m, row[k] * scale);
#pragma unroll
    for (int off = 1; off < 64; off <<= 1) m = fmaxf(m, __shfl_xor(m, off, 64));
    if (lane == 0) red[wave] = m;
    __syncthreads();
    float mb = fmaxf(fmaxf(red[0], red[1]), fmaxf(red[2], red[3]));
    __syncthreads();

    // pass 2: exp + sum; zero the masked tail so gemm_nn can run full-K
    float s = 0.f;
    for (int k = threadIdx.x; k < S; k += 256) {
        if (k < n) {
            float e = expf(row[k] * scale - mb);
            row[k] = e;
            s += e;
        } else {
            row[k] = 0.f;
        }
    }
#pragma unroll
    for (int off = 1; off < 64; off <<= 1) s += __shfl_xor(s, off, 64);
    if (lane == 0) red[wave] = s;
    __syncthreads();
    float sb = red[0] + red[1] + red[2] + red[3];
    float inv = 1.f / sb;

    // pass 3: normalize
    for (int k = threadIdx.x; k < n; k += 256) row[k] *= inv;
}

extern "C" void kernel_launch(void* const* d_in, const int* in_sizes, int n_in,
                              void* d_out, int out_size, void* d_ws, size_t ws_size,
                              hipStream_t stream) {
    const float* x  = (const float*)d_in[0];
    const float* Wq = (const float*)d_in[1];
    const float* Wk = (const float*)d_in[2];
    const float* Wv = (const float*)d_in[3];
    const float* Wo = (const float*)d_in[4];
    float* out = (float*)d_out;

    // Workspace layout (floats): per-batch Q,K,V,ctx [S,D] + one reused
    // score buffer [S,S]. Total = 4*2M + 4M = 12M floats = 48 MB.
    float* Qb  = (float*)d_ws;
    float* Kb  = Qb  + (size_t)SS * DD;
    float* Vb  = Kb  + (size_t)SS * DD;
    float* ctx = Vb  + (size_t)SS * DD;
    float* sc  = ctx + (size_t)SS * DD;

    dim3 blk(256);
    const float scale = 1.0f / 32.0f;  // 1/sqrt(1024)

    for (int b = 0; b < BB; ++b) {
        const float* xb = x + (size_t)b * SS * DD;
        float* outb = out + (size_t)b * SS * DV;

        // Projections: Q/K/V = xb @ W^T   [2048,1024] x [1024,1024]^T
        gemm_nt<<<dim3(DD / BN, SS / BM), blk, 0, stream>>>(xb, Wq, Qb, SS, DD, DD);
        gemm_nt<<<dim3(DD / BN, SS / BM), blk, 0, stream>>>(xb, Wk, Kb, SS, DD, DD);
        gemm_nt<<<dim3(DD / BN, SS / BM), blk, 0, stream>>>(xb, Wv, Vb, SS, DD, DD);

        // scores = Qb @ Kb^T  [2048,2048]
        gemm_nt<<<dim3(SS / BN, SS / BM), blk, 0, stream>>>(Qb, Kb, sc, SS, SS, DD);

        // causal softmax in place (masked tail zeroed)
        softmax_causal<<<dim3(SS), blk, 0, stream>>>(sc, SS, scale);

        // ctx = attn @ V  [2048,1024]
        gemm_nn<<<dim3(DD / BN, SS / BM), blk, 0, stream>>>(sc, Vb, ctx, SS, DD, SS);

        // out_b = ctx @ Wo^T  [2048,64]
        gemm_nt<<<dim3(DV / BN, SS / BM), blk, 0, stream>>>(ctx, Wo, outb, SS, DV, DD);
    }
}

// Round 2
// 366.716 us; speedup vs baseline: 8.8240x; 8.8240x over previous
//
#include <hip/hip_runtime.h>
#include <math.h>

typedef unsigned short u16;
typedef unsigned int u32;
typedef __attribute__((ext_vector_type(8))) short short8;
typedef __attribute__((ext_vector_type(4))) float f32x4;

#define BB 4
#define SS 2048
#define DD 1024
#define DV 64

__device__ __forceinline__ u16 f2bf(float f) {
    u32 u = __builtin_bit_cast(u32, f);
    u32 r = u + 0x7fffu + ((u >> 16) & 1u);  // RNE
    return (u16)(r >> 16);
}
__device__ __forceinline__ float bf2f(u16 b) {
    return __builtin_bit_cast(float, (u32)b << 16);
}
__device__ __forceinline__ void storeC(float* p, float v) { *p = v; }
__device__ __forceinline__ void storeC(u16* p, float v) { *p = f2bf(v); }

__global__ __launch_bounds__(256) void cast_f32_bf16(const float* __restrict__ in,
                                                     u16* __restrict__ out, int n) {
    int i = blockIdx.x * 256 + threadIdx.x;
    if (i < n) out[i] = f2bf(in[i]);
}

// C[M,N] = A[M,K] * B[N,K]^T, bf16 inputs, fp32 accumulate.
// MODE 0: plain. MODE 1: causal tile skip (scores; skip tiles with n0 > m0+TM-1).
// MODE 2: causal K-trim (attn*V; only k < m0+TM contributes).
// Per-z strides sA/sB/sC (elements) for batched launches.
template <int TM, int TN, int WM, int WN, typename OutT, int MODE>
__global__ __launch_bounds__(WM * WN * 64) void gemm_nt_mfma(
    const u16* __restrict__ A, const u16* __restrict__ B, OutT* __restrict__ C,
    int M, int N, int K, long sA, long sB, long sC) {
    static_assert(TM == WM * 64 && TN == WN * 64, "wave subtile must be 64x64");
    constexpr int NW = WM * WN;
    constexpr int CA = TM / 16;  // 1KB staging chunks for A tile [TM][32]
    constexpr int CB = TN / 16;

    const int z = blockIdx.z;
    A += (size_t)z * sA;
    B += (size_t)z * sB;
    C += (size_t)z * sC;
    const int m0 = blockIdx.y * TM, n0 = blockIdx.x * TN;
    if (MODE == 1 && n0 > m0 + TM - 1) return;  // fully-masked score tile
    const int Kend = (MODE == 2) ? min(K, m0 + TM) : K;

    __shared__ u16 As[TM * 32];
    __shared__ u16 Bs[TN * 32];

    const int tid = threadIdx.x;
    const int w = tid >> 6, lane = tid & 63;
    const int wm = w / WN, wn = w % WN;
    const int lrow = lane >> 2;          // staging: row within 16-row chunk
    const int lcol = (lane & 3) * 8;     // staging: 8-elem col block
    const int m16 = lane & 15;
    const int kh = (lane >> 4) * 8;      // k-half for A/B fragments

    f32x4 acc[4][4];
#pragma unroll
    for (int i = 0; i < 4; ++i)
#pragma unroll
        for (int j = 0; j < 4; ++j) acc[i][j] = (f32x4){0.f, 0.f, 0.f, 0.f};

    for (int k0 = 0; k0 < Kend; k0 += 32) {
        // global -> LDS staging, 16B/lane, wave-cyclic chunk assignment
        for (int c = w; c < CA; c += NW) {
            const u16* g = A + (size_t)(m0 + c * 16 + lrow) * K + k0 + lcol;
            __builtin_amdgcn_global_load_lds(
                (const __attribute__((address_space(1))) void*)g,
                (__attribute__((address_space(3))) void*)(&As[c * 512]), 16, 0, 0);
        }
        for (int c = w; c < CB; c += NW) {
            const u16* g = B + (size_t)(n0 + c * 16 + lrow) * K + k0 + lcol;
            __builtin_amdgcn_global_load_lds(
                (const __attribute__((address_space(1))) void*)g,
                (__attribute__((address_space(3))) void*)(&Bs[c * 512]), 16, 0, 0);
        }
        __syncthreads();

        short8 a[4], b[4];
#pragma unroll
        for (int i = 0; i < 4; ++i)
            a[i] = *(const short8*)&As[(wm * 64 + i * 16 + m16) * 32 + kh];
#pragma unroll
        for (int j = 0; j < 4; ++j)
            b[j] = *(const short8*)&Bs[(wn * 64 + j * 16 + m16) * 32 + kh];
#pragma unroll
        for (int i = 0; i < 4; ++i)
#pragma unroll
            for (int j = 0; j < 4; ++j)
                acc[i][j] = __builtin_amdgcn_mfma_f32_16x16x32_bf16(a[i], b[j], acc[i][j], 0, 0, 0);
        __syncthreads();
    }

    // epilogue: C/D layout col=lane&15, row=(lane>>4)*4+reg
    const int crow0 = m0 + wm * 64 + (lane >> 4) * 4;
    const int ccol0 = n0 + wn * 64 + m16;
#pragma unroll
    for (int i = 0; i < 4; ++i)
#pragma unroll
        for (int j = 0; j < 4; ++j)
#pragma unroll
            for (int r = 0; r < 4; ++r)
                storeC(&C[(size_t)(crow0 + i * 16 + r) * N + ccol0 + j * 16], acc[i][j][r]);
}

// In-place causal softmax on bf16 scores -> bf16 probs. One row per block.
// Zeroes the tail only up to the next 128 boundary (all the trimmed GEMM reads).
__global__ __launch_bounds__(256) void softmax_causal_bf16(u16* __restrict__ sc,
                                                           float scale) {
    const int q = blockIdx.x;
    u16* row = sc + (size_t)blockIdx.y * SS * SS + (size_t)q * SS;
    const int n = q + 1;
    const int zend = ((q >> 7) + 1) << 7;  // next multiple of 128 after q
    const int lane = threadIdx.x & 63;
    const int wave = threadIdx.x >> 6;
    __shared__ float red[4];

    float m = -INFINITY;
    for (int k = threadIdx.x; k < n; k += 256) m = fmaxf(m, bf2f(row[k]) * scale);
#pragma unroll
    for (int off = 1; off < 64; off <<= 1) m = fmaxf(m, __shfl_xor(m, off, 64));
    if (lane == 0) red[wave] = m;
    __syncthreads();
    const float mb = fmaxf(fmaxf(red[0], red[1]), fmaxf(red[2], red[3]));
    __syncthreads();

    float ev[8];
    int c = 0;
    float s = 0.f;
    for (int k = threadIdx.x; k < n; k += 256) {
        float e = __expf(bf2f(row[k]) * scale - mb);
        ev[c++] = e;
        s += e;
    }
#pragma unroll
    for (int off = 1; off < 64; off <<= 1) s += __shfl_xor(s, off, 64);
    if (lane == 0) red[wave] = s;
    __syncthreads();
    const float inv = 1.f / (red[0] + red[1] + red[2] + red[3]);

    c = 0;
    for (int k = threadIdx.x; k < zend; k += 256)
        row[k] = (k < n) ? f2bf(ev[c++] * inv) : (u16)0;
}

extern "C" void kernel_launch(void* const* d_in, const int* in_sizes, int n_in,
                              void* d_out, int out_size, void* d_ws, size_t ws_size,
                              hipStream_t stream) {
    const float* x  = (const float*)d_in[0];
    const float* Wq = (const float*)d_in[1];
    const float* Wk = (const float*)d_in[2];
    const float* Wv = (const float*)d_in[3];
    const float* Wo = (const float*)d_in[4];
    float* out = (float*)d_out;

    // ws layout (u16 elements), ~107 MB total
    u16* x16  = (u16*)d_ws;                          // [4*2048,1024]
    u16* Wq16 = x16  + (size_t)BB * SS * DD;         // [1024,1024]
    u16* Wk16 = Wq16 + (size_t)DD * DD;
    u16* Wv16 = Wk16 + (size_t)DD * DD;
    u16* Wo16 = Wv16 + (size_t)DD * DD;              // [64,1024]
    u16* Q16  = Wo16 + (size_t)DV * DD;              // [4*2048,1024]; aliased as ctx16 later
    u16* K16  = Q16  + (size_t)BB * SS * DD;
    u16* Vt16 = K16  + (size_t)BB * SS * DD;         // [4][1024,2048]
    u16* sc16 = Vt16 + (size_t)BB * DD * SS;         // [4][2048,2048]
    u16* ctx16 = Q16;  // Q dead after scores

    const float scale = 1.0f / 32.0f;

    // casts
    cast_f32_bf16<<<dim3((BB * SS * DD + 255) / 256), 256, 0, stream>>>(x, x16, BB * SS * DD);
    cast_f32_bf16<<<dim3((DD * DD + 255) / 256), 256, 0, stream>>>(Wq, Wq16, DD * DD);
    cast_f32_bf16<<<dim3((DD * DD + 255) / 256), 256, 0, stream>>>(Wk, Wk16, DD * DD);
    cast_f32_bf16<<<dim3((DD * DD + 255) / 256), 256, 0, stream>>>(Wv, Wv16, DD * DD);
    cast_f32_bf16<<<dim3((DV * DD + 255) / 256), 256, 0, stream>>>(Wo, Wo16, DV * DD);

    // Q = x @ Wq^T, K = x @ Wk^T  (all batches as one M=8192 GEMM)
    gemm_nt_mfma<128, 128, 2, 2, u16, 0><<<dim3(DD / 128, BB * SS / 128, 1), 256, 0, stream>>>(
        x16, Wq16, Q16, BB * SS, DD, DD, 0, 0, 0);
    gemm_nt_mfma<128, 128, 2, 2, u16, 0><<<dim3(DD / 128, BB * SS / 128, 1), 256, 0, stream>>>(
        x16, Wk16, K16, BB * SS, DD, DD, 0, 0, 0);

    // Vt_b = Wv @ x_b^T : M=1024, N=2048, K=1024, batched over z
    gemm_nt_mfma<128, 128, 2, 2, u16, 0><<<dim3(SS / 128, DD / 128, BB), 256, 0, stream>>>(
        Wv16, x16, Vt16, DD, SS, DD, 0, (long)SS * DD, (long)DD * SS);

    // scores_b = Q_b @ K_b^T with causal tile skip
    gemm_nt_mfma<128, 128, 2, 2, u16, 1><<<dim3(SS / 128, SS / 128, BB), 256, 0, stream>>>(
        Q16, K16, sc16, SS, SS, DD, (long)SS * DD, (long)SS * DD, (long)SS * SS);

    // causal softmax in place
    softmax_causal_bf16<<<dim3(SS, BB), 256, 0, stream>>>(sc16, scale);

    // ctx_b = P_b @ V_b = P_b @ Vt_b^T with causal K-trim
    gemm_nt_mfma<128, 128, 2, 2, u16, 2><<<dim3(DD / 128, SS / 128, BB), 256, 0, stream>>>(
        sc16, Vt16, ctx16, SS, DD, SS, (long)SS * SS, (long)DD * SS, (long)SS * DD);

    // out = ctx @ Wo^T : M=8192, N=64 (TN=64 variant, 128 threads)
    gemm_nt_mfma<128, 64, 2, 1, float, 0><<<dim3(1, BB * SS / 128, 1), 128, 0, stream>>>(
        ctx16, Wo16, out, BB * SS, DV, DD, 0, 0, 0);
}

// Round 3
// 348.180 us; speedup vs baseline: 9.2937x; 1.0532x over previous
//
#include <hip/hip_runtime.h>
#include <math.h>

typedef unsigned short u16;
typedef unsigned int u32;
typedef __attribute__((ext_vector_type(8))) short short8;
typedef __attribute__((ext_vector_type(4))) short short4v;
typedef __attribute__((ext_vector_type(4))) float f32x4;

#define BB 4
#define SS 2048
#define DD 1024
#define DV 64

__device__ __forceinline__ u16 f2bf(float f) {
    u32 u = __builtin_bit_cast(u32, f);
    u32 r = u + 0x7fffu + ((u >> 16) & 1u);  // RNE
    return (u16)(r >> 16);
}
__device__ __forceinline__ float bf2f(u16 b) {
    return __builtin_bit_cast(float, (u32)b << 16);
}
__device__ __forceinline__ void storeC(float* p, float v) { *p = v; }
__device__ __forceinline__ void storeC(u16* p, float v) { *p = f2bf(v); }

// vectorized fp32 -> bf16 cast, 4 elems/thread
__global__ __launch_bounds__(256) void cast4_f32_bf16(const float* __restrict__ in,
                                                      u16* __restrict__ out, int n4) {
    int i = blockIdx.x * 256 + threadIdx.x;
    if (i < n4) {
        f32x4 v = ((const f32x4*)in)[i];
        short4v o;
        o.x = (short)f2bf(v.x); o.y = (short)f2bf(v.y);
        o.z = (short)f2bf(v.z); o.w = (short)f2bf(v.w);
        ((short4v*)out)[i] = o;
    }
}

// Wvo[o,e] = sum_d Wo[o,d] * Wv[d,e]  (fp32 accumulate, bf16 out)
// one block per output row o; thread covers 4 contiguous e.
__global__ __launch_bounds__(256) void wvo_nn(const float* __restrict__ Wo,
                                              const float* __restrict__ Wv,
                                              u16* __restrict__ out) {
    const int o = blockIdx.x;
    const int e0 = threadIdx.x * 4;
    float acc0 = 0.f, acc1 = 0.f, acc2 = 0.f, acc3 = 0.f;
    for (int d = 0; d < DD; ++d) {
        float s = Wo[o * DD + d];
        f32x4 w = *(const f32x4*)&Wv[(size_t)d * DD + e0];
        acc0 += s * w.x; acc1 += s * w.y; acc2 += s * w.z; acc3 += s * w.w;
    }
    out[o * DD + e0 + 0] = f2bf(acc0);
    out[o * DD + e0 + 1] = f2bf(acc1);
    out[o * DD + e0 + 2] = f2bf(acc2);
    out[o * DD + e0 + 3] = f2bf(acc3);
}

// C[M,N] = A[M,K] * B[N,K]^T, bf16 in, fp32 acc. Arbitrary leading dims.
// MODE 0: plain. MODE 1: causal tile skip (skip n0 > m0+TM-1).
// MODE 2: causal K-trim (Kend = min(K, m0+TM)).
template <int TM, int TN, int WM, int WN, typename OutT, int MODE>
__global__ __launch_bounds__(WM * WN * 64) void gemm_nt_mfma(
    const u16* __restrict__ A, const u16* __restrict__ B, OutT* __restrict__ C,
    int lda, int ldb, int ldc, int K, long sA, long sB, long sC) {
    static_assert(TM == WM * 64 || (TM == 64 && WM == 1), "tile/wave mismatch");
    constexpr int NW = WM * WN;
    constexpr int CA = TM / 16;
    constexpr int CB = TN / 16;

    const int z = blockIdx.z;
    A += (size_t)z * sA;
    B += (size_t)z * sB;
    C += (size_t)z * sC;
    const int m0 = blockIdx.y * TM, n0 = blockIdx.x * TN;
    if (MODE == 1 && n0 > m0 + TM - 1) return;
    const int Kend = (MODE == 2) ? min(K, m0 + TM) : K;

    __shared__ u16 As[TM * 32];
    __shared__ u16 Bs[TN * 32];

    const int tid = threadIdx.x;
    const int w = tid >> 6, lane = tid & 63;
    const int wm = w / WN, wn = w % WN;
    const int lrow = lane >> 2;
    const int lcol = (lane & 3) * 8;
    const int m16 = lane & 15;
    const int kh = (lane >> 4) * 8;

    f32x4 acc[4][4];
#pragma unroll
    for (int i = 0; i < 4; ++i)
#pragma unroll
        for (int j = 0; j < 4; ++j) acc[i][j] = (f32x4){0.f, 0.f, 0.f, 0.f};

    for (int k0 = 0; k0 < Kend; k0 += 32) {
        for (int c = w; c < CA; c += NW) {
            const u16* g = A + (size_t)(m0 + c * 16 + lrow) * lda + k0 + lcol;
            __builtin_amdgcn_global_load_lds(
                (const __attribute__((address_space(1))) void*)g,
                (__attribute__((address_space(3))) void*)(&As[c * 512]), 16, 0, 0);
        }
        for (int c = w; c < CB; c += NW) {
            const u16* g = B + (size_t)(n0 + c * 16 + lrow) * ldb + k0 + lcol;
            __builtin_amdgcn_global_load_lds(
                (const __attribute__((address_space(1))) void*)g,
                (__attribute__((address_space(3))) void*)(&Bs[c * 512]), 16, 0, 0);
        }
        __syncthreads();

        short8 a[4], b[4];
#pragma unroll
        for (int i = 0; i < 4; ++i)
            a[i] = *(const short8*)&As[(wm * 64 + i * 16 + m16) * 32 + kh];
#pragma unroll
        for (int j = 0; j < 4; ++j)
            b[j] = *(const short8*)&Bs[(wn * 64 + j * 16 + m16) * 32 + kh];
#pragma unroll
        for (int i = 0; i < 4; ++i)
#pragma unroll
            for (int j = 0; j < 4; ++j)
                acc[i][j] = __builtin_amdgcn_mfma_f32_16x16x32_bf16(a[i], b[j], acc[i][j], 0, 0, 0);
        __syncthreads();
    }

    const int crow0 = m0 + wm * 64 + (lane >> 4) * 4;
    const int ccol0 = n0 + wn * 64 + m16;
#pragma unroll
    for (int i = 0; i < 4; ++i)
#pragma unroll
        for (int j = 0; j < 4; ++j)
#pragma unroll
            for (int r = 0; r < 4; ++r)
                storeC(&C[(size_t)(crow0 + i * 16 + r) * ldc + ccol0 + j * 16], acc[i][j][r]);
}

// In-place causal softmax on bf16 scores. One row per block; zeroes tail to
// the next 128 boundary (exactly what the K-trimmed PV GEMM reads).
__global__ __launch_bounds__(256) void softmax_causal_bf16(u16* __restrict__ sc,
                                                           float scale) {
    const int q = blockIdx.x;
    u16* row = sc + (size_t)blockIdx.y * SS * SS + (size_t)q * SS;
    const int n = q + 1;
    const int zend = ((q >> 7) + 1) << 7;
    const int lane = threadIdx.x & 63;
    const int wave = threadIdx.x >> 6;
    __shared__ float red[4];

    float m = -INFINITY;
    for (int k = threadIdx.x; k < n; k += 256) m = fmaxf(m, bf2f(row[k]) * scale);
#pragma unroll
    for (int off = 1; off < 64; off <<= 1) m = fmaxf(m, __shfl_xor(m, off, 64));
    if (lane == 0) red[wave] = m;
    __syncthreads();
    const float mb = fmaxf(fmaxf(red[0], red[1]), fmaxf(red[2], red[3]));
    __syncthreads();

    float ev[8];
    int c = 0;
    float s = 0.f;
    for (int k = threadIdx.x; k < n; k += 256) {
        float e = __expf(bf2f(row[k]) * scale - mb);
        ev[c++] = e;
        s += e;
    }
#pragma unroll
    for (int off = 1; off < 64; off <<= 1) s += __shfl_xor(s, off, 64);
    if (lane == 0) red[wave] = s;
    __syncthreads();
    const float inv = 1.f / (red[0] + red[1] + red[2] + red[3]);

    c = 0;
    for (int k = threadIdx.x; k < zend; k += 256)
        row[k] = (k < n) ? f2bf(ev[c++] * inv) : (u16)0;
}

extern "C" void kernel_launch(void* const* d_in, const int* in_sizes, int n_in,
                              void* d_out, int out_size, void* d_ws, size_t ws_size,
                              hipStream_t stream) {
    const float* x  = (const float*)d_in[0];
    const float* Wq = (const float*)d_in[1];
    const float* Wk = (const float*)d_in[2];
    const float* Wv = (const float*)d_in[3];
    const float* Wo = (const float*)d_in[4];
    float* out = (float*)d_out;

    // ws layout (u16 elems), ~89 MB
    u16* x16   = (u16*)d_ws;                           // [8192,1024]
    u16* Wqk16 = x16   + (size_t)BB * SS * DD;         // [2048,1024] = [Wq;Wk]
    u16* Wvo16 = Wqk16 + (size_t)2 * DD * DD;          // [64,1024]  = Wo@Wv
    u16* QK16  = Wvo16 + (size_t)DV * DD;              // [8192,2048]
    u16* Ut16  = QK16  + (size_t)BB * SS * 2 * DD;     // [64,8192]  = (x@Wvo^T)^T
    u16* sc16  = Ut16  + (size_t)DV * BB * SS;         // [4][2048,2048]

    const float scale = 1.0f / 32.0f;

    // casts (vectorized)
    cast4_f32_bf16<<<dim3(BB * SS * DD / 4 / 256), 256, 0, stream>>>(x, x16, BB * SS * DD / 4);
    cast4_f32_bf16<<<dim3(DD * DD / 4 / 256), 256, 0, stream>>>(Wq, Wqk16, DD * DD / 4);
    cast4_f32_bf16<<<dim3(DD * DD / 4 / 256), 256, 0, stream>>>(Wk, Wqk16 + (size_t)DD * DD, DD * DD / 4);

    // Wvo = Wo @ Wv (fp32 accumulate)
    wvo_nn<<<dim3(DV), 256, 0, stream>>>(Wo, Wv, Wvo16);

    // [Q|K] = x @ [Wq;Wk]^T : M=8192, N=2048, K=1024 -> 1024 blocks
    gemm_nt_mfma<128, 128, 2, 2, u16, 0><<<dim3(2 * DD / 128, BB * SS / 128, 1), 256, 0, stream>>>(
        x16, Wqk16, QK16, DD, DD, 2 * DD, DD, 0, 0, 0);

    // Ut = Wvo @ x^T : M=64, N=8192, K=1024  (C row-major [64,8192])
    gemm_nt_mfma<64, 128, 1, 2, u16, 0><<<dim3(BB * SS / 128, 1, 1), 128, 0, stream>>>(
        Wvo16, x16, Ut16, DD, DD, BB * SS, DD, 0, 0, 0);

    // scores_b = Q_b @ K_b^T, causal tile skip. Q/K are column halves of QK16.
    gemm_nt_mfma<128, 128, 2, 2, u16, 1><<<dim3(SS / 128, SS / 128, BB), 256, 0, stream>>>(
        QK16, QK16 + DD, sc16, 2 * DD, 2 * DD, SS, DD,
        (long)SS * 2 * DD, (long)SS * 2 * DD, (long)SS * SS);

    // causal softmax in place
    softmax_causal_bf16<<<dim3(SS, BB), 256, 0, stream>>>(sc16, scale);

    // out_b = P_b @ Ut_b^T : M=2048, N=64, K=2048 trimmed; Ut_b = cols [b*2048,...)
    gemm_nt_mfma<64, 64, 1, 1, float, 2><<<dim3(1, SS / 64, BB), 64, 0, stream>>>(
        sc16, Ut16, out, SS, BB * SS, DV, SS,
        (long)SS * SS, (long)SS, (long)SS * DV);
}

// Round 4
// 269.095 us; speedup vs baseline: 12.0251x; 1.2939x over previous
//
#include <hip/hip_runtime.h>
#include <math.h>

typedef unsigned short u16;
typedef unsigned int u32;
typedef __attribute__((ext_vector_type(8))) short short8;
typedef __attribute__((ext_vector_type(4))) short short4v;
typedef __attribute__((ext_vector_type(4))) float f32x4;

#define BB 4
#define SS 2048
#define DD 1024
#define DV 64
#define NQKU 2176  // 1024 Q + 1024 K + 64 U + 64 pad

__device__ __forceinline__ u16 f2bf(float f) {
    u32 u = __builtin_bit_cast(u32, f);
    u32 r = u + 0x7fffu + ((u >> 16) & 1u);  // RNE
    return (u16)(r >> 16);
}
__device__ __forceinline__ float bf2f(u16 b) {
    return __builtin_bit_cast(float, (u32)b << 16);
}
__device__ __forceinline__ void storeC(float* p, float v) { *p = v; }
__device__ __forceinline__ void storeC(u16* p, float v) { *p = f2bf(v); }

// vectorized fp32 -> bf16 cast, 4 elems/thread
__global__ __launch_bounds__(256) void cast4_f32_bf16(const float* __restrict__ in,
                                                      u16* __restrict__ out, int n4) {
    int i = blockIdx.x * 256 + threadIdx.x;
    if (i < n4) {
        f32x4 v = ((const f32x4*)in)[i];
        short4v o;
        o.x = (short)f2bf(v.x); o.y = (short)f2bf(v.y);
        o.z = (short)f2bf(v.z); o.w = (short)f2bf(v.w);
        ((short4v*)out)[i] = o;
    }
}

// Wvo = Wo @ Wv, K-split partials. grid(16 o-quads, 8 k-chunks), 256 thr.
// part[kc][o][e] fp32.
__global__ __launch_bounds__(256) void wvo_partial(const float* __restrict__ Wo,
                                                   const float* __restrict__ Wv,
                                                   float* __restrict__ part) {
    const int ob = blockIdx.x * 4;
    const int kc = blockIdx.y;
    const int kbase = kc * 128;
    const int e0 = threadIdx.x * 4;
    __shared__ float wo_s[4 * 128];
    for (int i = threadIdx.x; i < 512; i += 256)
        wo_s[i] = Wo[(size_t)(ob + (i >> 7)) * DD + kbase + (i & 127)];
    __syncthreads();

    float acc[4][4] = {};
#pragma unroll 4
    for (int k = 0; k < 128; ++k) {
        f32x4 w = *(const f32x4*)&Wv[(size_t)(kbase + k) * DD + e0];
#pragma unroll
        for (int oi = 0; oi < 4; ++oi) {
            float s = wo_s[oi * 128 + k];
            acc[oi][0] += s * w.x; acc[oi][1] += s * w.y;
            acc[oi][2] += s * w.z; acc[oi][3] += s * w.w;
        }
    }
#pragma unroll
    for (int oi = 0; oi < 4; ++oi)
        *(f32x4*)&part[((size_t)kc * 64 + ob + oi) * DD + e0] =
            (f32x4){acc[oi][0], acc[oi][1], acc[oi][2], acc[oi][3]};
}

// reduce 8 partials, write bf16 into W_all rows 2048..2111
__global__ __launch_bounds__(256) void wvo_reduce(const float* __restrict__ part,
                                                  u16* __restrict__ Wall) {
    const int o = blockIdx.x;
    const int e0 = threadIdx.x * 4;
    f32x4 s = (f32x4){0.f, 0.f, 0.f, 0.f};
#pragma unroll
    for (int kc = 0; kc < 8; ++kc)
        s += *(const f32x4*)&part[((size_t)kc * 64 + o) * DD + e0];
    short4v ov;
    ov.x = (short)f2bf(s.x); ov.y = (short)f2bf(s.y);
    ov.z = (short)f2bf(s.z); ov.w = (short)f2bf(s.w);
    *(short4v*)&Wall[(size_t)(2048 + o) * DD + e0] = ov;
}

// C[M,N] = A[M,K] * B[N,K]^T, bf16 in, fp32 acc.
// MODE 0: plain. MODE 1: causal tile skip (skip n0 > m0+TM-1).
template <int TM, int TN, int WM, int WN, typename OutT, int MODE>
__global__ __launch_bounds__(WM * WN * 64) void gemm_nt_mfma(
    const u16* __restrict__ A, const u16* __restrict__ B, OutT* __restrict__ C,
    int lda, int ldb, int ldc, int K, long sA, long sB, long sC) {
    constexpr int NW = WM * WN;
    constexpr int CA = TM / 16;
    constexpr int CB = TN / 16;

    const int z = blockIdx.z;
    A += (size_t)z * sA;
    B += (size_t)z * sB;
    C += (size_t)z * sC;
    const int m0 = blockIdx.y * TM, n0 = blockIdx.x * TN;
    if (MODE == 1 && n0 > m0 + TM - 1) return;

    __shared__ u16 As[TM * 32];
    __shared__ u16 Bs[TN * 32];

    const int tid = threadIdx.x;
    const int w = tid >> 6, lane = tid & 63;
    const int wm = w / WN, wn = w % WN;
    const int lrow = lane >> 2;
    const int lcol = (lane & 3) * 8;
    const int m16 = lane & 15;
    const int kh = (lane >> 4) * 8;

    f32x4 acc[4][4];
#pragma unroll
    for (int i = 0; i < 4; ++i)
#pragma unroll
        for (int j = 0; j < 4; ++j) acc[i][j] = (f32x4){0.f, 0.f, 0.f, 0.f};

    for (int k0 = 0; k0 < K; k0 += 32) {
        for (int c = w; c < CA; c += NW) {
            const u16* g = A + (size_t)(m0 + c * 16 + lrow) * lda + k0 + lcol;
            __builtin_amdgcn_global_load_lds(
                (const __attribute__((address_space(1))) void*)g,
                (__attribute__((address_space(3))) void*)(&As[c * 512]), 16, 0, 0);
        }
        for (int c = w; c < CB; c += NW) {
            const u16* g = B + (size_t)(n0 + c * 16 + lrow) * ldb + k0 + lcol;
            __builtin_amdgcn_global_load_lds(
                (const __attribute__((address_space(1))) void*)g,
                (__attribute__((address_space(3))) void*)(&Bs[c * 512]), 16, 0, 0);
        }
        __syncthreads();

        short8 a[4], b[4];
#pragma unroll
        for (int i = 0; i < 4; ++i)
            a[i] = *(const short8*)&As[(wm * 64 + i * 16 + m16) * 32 + kh];
#pragma unroll
        for (int j = 0; j < 4; ++j)
            b[j] = *(const short8*)&Bs[(wn * 64 + j * 16 + m16) * 32 + kh];
#pragma unroll
        for (int i = 0; i < 4; ++i)
#pragma unroll
            for (int j = 0; j < 4; ++j)
                acc[i][j] = __builtin_amdgcn_mfma_f32_16x16x32_bf16(a[i], b[j], acc[i][j], 0, 0, 0);
        __syncthreads();
    }

    const int crow0 = m0 + wm * 64 + (lane >> 4) * 4;
    const int ccol0 = n0 + wn * 64 + m16;
#pragma unroll
    for (int i = 0; i < 4; ++i)
#pragma unroll
        for (int j = 0; j < 4; ++j)
#pragma unroll
            for (int r = 0; r < 4; ++r)
                storeC(&C[(size_t)(crow0 + i * 16 + r) * ldc + ccol0 + j * 16], acc[i][j][r]);
}

// In-place causal softmax on bf16 scores; zeroes tail to next 128 boundary.
__global__ __launch_bounds__(256) void softmax_causal_bf16(u16* __restrict__ sc,
                                                           float scale) {
    const int q = blockIdx.x;
    u16* row = sc + (size_t)blockIdx.y * SS * SS + (size_t)q * SS;
    const int n = q + 1;
    const int zend = ((q >> 7) + 1) << 7;
    const int lane = threadIdx.x & 63;
    const int wave = threadIdx.x >> 6;
    __shared__ float red[4];

    float m = -INFINITY;
    for (int k = threadIdx.x; k < n; k += 256) m = fmaxf(m, bf2f(row[k]) * scale);
#pragma unroll
    for (int off = 1; off < 64; off <<= 1) m = fmaxf(m, __shfl_xor(m, off, 64));
    if (lane == 0) red[wave] = m;
    __syncthreads();
    const float mb = fmaxf(fmaxf(red[0], red[1]), fmaxf(red[2], red[3]));
    __syncthreads();

    float ev[8];
    int c = 0;
    float s = 0.f;
    for (int k = threadIdx.x; k < n; k += 256) {
        float e = __expf(bf2f(row[k]) * scale - mb);
        ev[c++] = e;
        s += e;
    }
#pragma unroll
    for (int off = 1; off < 64; off <<= 1) s += __shfl_xor(s, off, 64);
    if (lane == 0) red[wave] = s;
    __syncthreads();
    const float inv = 1.f / (red[0] + red[1] + red[2] + red[3]);

    c = 0;
    for (int k = threadIdx.x; k < zend; k += 256)
        row[k] = (k < n) ? f2bf(ev[c++] * inv) : (u16)0;
}

// Ut[o][s] = QKU[s][2048+o]; grid(128 s-tiles of 64), 256 thr.
__global__ __launch_bounds__(256) void transpose_u(const u16* __restrict__ QKU,
                                                   u16* __restrict__ Ut) {
    __shared__ u16 t[64][72];
    const int s0 = blockIdx.x * 64;
    const int g = threadIdx.x >> 6, lane = threadIdx.x & 63;
    for (int r = g; r < 64; r += 4)
        t[r][lane] = QKU[(size_t)(s0 + r) * NQKU + 2048 + lane];
    __syncthreads();
    for (int r = g; r < 64; r += 4)
        Ut[(size_t)r * (BB * SS) + s0 + lane] = t[lane][r];
}

// out_b = P_b @ Ut_b^T  (M=2048, N=64, K trimmed to m0+64).
// 4 waves round-robin K-chunks, register-direct loads, LDS cross-wave reduce.
__global__ __launch_bounds__(256) void pv_nt(const u16* __restrict__ P,
                                             const u16* __restrict__ Ut,
                                             float* __restrict__ out) {
    const int z = blockIdx.y;
    const u16* Pz = P + (size_t)z * SS * SS;
    const u16* Uz = Ut + (size_t)z * SS;  // column offset into [64, 8192]
    float* oz = out + (size_t)z * SS * DV;
    const int m0 = blockIdx.x * 64;
    const int Kend = m0 + 64;
    const int w = threadIdx.x >> 6, lane = threadIdx.x & 63;
    const int m16 = lane & 15, kh = (lane >> 4) * 8;

    f32x4 acc[4][4];
#pragma unroll
    for (int i = 0; i < 4; ++i)
#pragma unroll
        for (int j = 0; j < 4; ++j) acc[i][j] = (f32x4){0.f, 0.f, 0.f, 0.f};

    for (int k0 = w * 32; k0 < Kend; k0 += 128) {
        short8 a[4], b[4];
#pragma unroll
        for (int i = 0; i < 4; ++i)
            a[i] = *(const short8*)&Pz[(size_t)(m0 + i * 16 + m16) * SS + k0 + kh];
#pragma unroll
        for (int j = 0; j < 4; ++j)
            b[j] = *(const short8*)&Uz[(size_t)(j * 16 + m16) * (BB * SS) + k0 + kh];
#pragma unroll
        for (int i = 0; i < 4; ++i)
#pragma unroll
            for (int j = 0; j < 4; ++j)
                acc[i][j] = __builtin_amdgcn_mfma_f32_16x16x32_bf16(a[i], b[j], acc[i][j], 0, 0, 0);
    }

    __shared__ float buf[2][64 * 64];
    const int rbase = (lane >> 4) * 4;
    if (w < 2) {
#pragma unroll
        for (int i = 0; i < 4; ++i)
#pragma unroll
            for (int j = 0; j < 4; ++j)
#pragma unroll
                for (int r = 0; r < 4; ++r)
                    buf[w][(i * 16 + rbase + r) * 64 + j * 16 + m16] = acc[i][j][r];
    }
    __syncthreads();
    if (w >= 2) {
#pragma unroll
        for (int i = 0; i < 4; ++i)
#pragma unroll
            for (int j = 0; j < 4; ++j)
#pragma unroll
                for (int r = 0; r < 4; ++r)
                    buf[w - 2][(i * 16 + rbase + r) * 64 + j * 16 + m16] += acc[i][j][r];
    }
    __syncthreads();
    for (int idx = threadIdx.x; idx < 64 * 64; idx += 256)
        oz[(size_t)(m0 + (idx >> 6)) * DV + (idx & 63)] = buf[0][idx] + buf[1][idx];
}

extern "C" void kernel_launch(void* const* d_in, const int* in_sizes, int n_in,
                              void* d_out, int out_size, void* d_ws, size_t ws_size,
                              hipStream_t stream) {
    const float* x  = (const float*)d_in[0];
    const float* Wq = (const float*)d_in[1];
    const float* Wk = (const float*)d_in[2];
    const float* Wv = (const float*)d_in[3];
    const float* Wo = (const float*)d_in[4];
    float* out = (float*)d_out;

    // ws layout
    u16* x16  = (u16*)d_ws;                            // [8192,1024]
    u16* Wall = x16 + (size_t)BB * SS * DD;            // [2176,1024]: Wq;Wk;Wvo;pad
    u16* QKU  = Wall + (size_t)NQKU * DD;              // [8192,2176]
    u16* Ut   = QKU + (size_t)BB * SS * NQKU;          // [64,8192]
    u16* sc16 = Ut + (size_t)DV * BB * SS;             // [4][2048,2048]
    float* part = (float*)(sc16 + (size_t)BB * SS * SS);  // [8][64][1024] fp32

    const float scale = 1.0f / 32.0f;

    cast4_f32_bf16<<<dim3(BB * SS * DD / 4 / 256), 256, 0, stream>>>(x, x16, BB * SS * DD / 4);
    cast4_f32_bf16<<<dim3(DD * DD / 4 / 256), 256, 0, stream>>>(Wq, Wall, DD * DD / 4);
    cast4_f32_bf16<<<dim3(DD * DD / 4 / 256), 256, 0, stream>>>(Wk, Wall + (size_t)DD * DD, DD * DD / 4);

    // Wvo = Wo @ Wv -> Wall rows 2048..2111
    wvo_partial<<<dim3(16, 8), 256, 0, stream>>>(Wo, Wv, part);
    wvo_reduce<<<dim3(64), 256, 0, stream>>>(part, Wall);

    // [Q|K|U] = x @ Wall^T : M=8192, N=2176, K=1024
    gemm_nt_mfma<128, 128, 2, 2, u16, 0><<<dim3(NQKU / 128, BB * SS / 128, 1), 256, 0, stream>>>(
        x16, Wall, QKU, DD, DD, NQKU, DD, 0, 0, 0);

    // scores_b = Q_b @ K_b^T (causal tile skip)
    gemm_nt_mfma<128, 128, 2, 2, u16, 1><<<dim3(SS / 128, SS / 128, BB), 256, 0, stream>>>(
        QKU, QKU + DD, sc16, NQKU, NQKU, SS, DD,
        (long)SS * NQKU, (long)SS * NQKU, (long)SS * SS);

    softmax_causal_bf16<<<dim3(SS, BB), 256, 0, stream>>>(sc16, scale);

    transpose_u<<<dim3(BB * SS / 64), 256, 0, stream>>>(QKU, Ut);

    pv_nt<<<dim3(SS / 64, BB), 256, 0, stream>>>(sc16, Ut, out);
}